// Round 9
// baseline (182.857 us; speedup 1.0000x reference)
//
#include <hip/hip_runtime.h>
#include <hip/hip_bf16.h>

#define NE 100
#define NB 4096
#define ND 256
#define NF 32
#define NH 16
#define NL 8
#define BT 256   // batch rows per block

typedef float  floatx4 __attribute__((ext_vector_type(4)));
typedef short  short8  __attribute__((ext_vector_type(8)));

__device__ __forceinline__ float sigf(float a) {
    return __builtin_amdgcn_rcpf(1.0f + __expf(-a));
}
__device__ __forceinline__ unsigned short f2bf_rne(float f) {
    unsigned u = __float_as_uint(f);
    unsigned r = u + 0x7FFFu + ((u >> 16) & 1u);
    return (unsigned short)(r >> 16);
}
__device__ __forceinline__ float bf2f(unsigned short h) {
    return __uint_as_float(((unsigned)h) << 16);
}

// Fused: phase1 per-row MLP (VALU) -> bf16 hi/lo fragments in LDS ->
// phase2 [256x32]@[32x256] via mfma_f32_16x16x32_bf16, OPERANDS SWAPPED:
//   mfma(A-slot = Wo-frag, B-slot = d1-frag) computes G' = Wo_t^T . d1_t^T,
//   so lane holds G'[cols 4*(l>>4)+reg][row l&15] -> 4 consecutive OUTPUT
//   columns of one row per lane -> dwordx4 stores (R8's scalar-store fix).
// Identical fragment construction for both operands cancels the HW k-map
// (proven by R8 passing).
__global__ __launch_bounds__(256, 2)
void bagae_mfma(const float* __restrict__ x,
                const int* __restrict__ idx,
                const float* __restrict__ We0, const float* __restrict__ be0,
                const float* __restrict__ We1, const float* __restrict__ be1,
                const float* __restrict__ Wl,  const float* __restrict__ bl,
                const float* __restrict__ Wd0, const float* __restrict__ bd0,
                const float* __restrict__ Wd1, const float* __restrict__ bd1,
                const float* __restrict__ Wo,  const float* __restrict__ bo,
                float* __restrict__ out)
{
    __shared__ short sAhi[BT * NF];   // 16 KB, fragment-ordered d1 (hi)
    __shared__ short sAlo[BT * NF];   // 16 KB (lo residual)
    __shared__ short sBhi[ND * NF];   // 16 KB, fragment-ordered Wo (hi)
    __shared__ short sBlo[ND * NF];   // 16 KB (lo residual)
    __shared__ float s_We0[NF * NH];
    __shared__ float s_We1[NH * NL];
    __shared__ float s_Wl [NL * NL];
    __shared__ float s_Wd0[NL * NH];
    __shared__ float s_Wd1[NH * NF];
    __shared__ float s_be0[NH], s_be1[NL], s_bl[NL], s_bd0[NH], s_bd1[NF];
    __shared__ int   s_idx[NF];

    const int tid = threadIdx.x;
    const int e   = blockIdx.y;
    const int b0  = blockIdx.x * BT;

    // ---- stage small per-estimator weights ----
    {
        const float* We0e = We0 + e * (NF * NH);
        const float* Wd1e = Wd1 + e * (NH * NF);
        for (int i = tid; i < NF * NH; i += 256) { s_We0[i] = We0e[i]; s_Wd1[i] = Wd1e[i]; }
        if (tid < NH * NL) { s_We1[tid] = We1[e * NH * NL + tid];
                             s_Wd0[tid] = Wd0[e * NL * NH + tid]; }
        if (tid < NL * NL) { s_Wl[tid]  = Wl [e * NL * NL + tid]; }
        if (tid < NF)      { s_idx[tid] = idx[e * NF + tid];
                             s_bd1[tid] = bd1[e * NF + tid]; }
        if (tid < NH)      { s_be0[tid] = be0[e * NH + tid];
                             s_bd0[tid] = bd0[e * NH + tid]; }
        if (tid < NL)      { s_be1[tid] = be1[e * NL + tid];
                             s_bl [tid] = bl [e * NL + tid]; }
    }

    // ---- stage B = Wo_e column tid as hi/lo bf16 fragments ----
    {
        const float* Woe = Wo + (long)e * NF * ND;
        float wcol[NF];
        #pragma unroll
        for (int k = 0; k < NF; ++k) wcol[k] = Woe[k * ND + tid];   // coalesced across lanes
        const int ct = tid >> 4, c16 = tid & 15;
        #pragma unroll
        for (int kc = 0; kc < 4; ++kc) {
            short8 hi, lo;
            #pragma unroll
            for (int j = 0; j < 8; ++j) {
                float v = wcol[kc * 8 + j];
                unsigned short h = f2bf_rne(v);
                hi[j] = (short)h;
                lo[j] = (short)f2bf_rne(v - bf2f(h));
            }
            const int u = (ct * 4 + kc) * 16 + c16;
            *reinterpret_cast<short8*>(&sBhi[u * 8]) = hi;
            *reinterpret_cast<short8*>(&sBlo[u * 8]) = lo;
        }
    }
    __syncthreads();

    // ---- phase 1: per-row MLP chain -> d1[32] (relu) -> A fragments ----
    {
        const float* xrow = x + (long)(b0 + tid) * ND;

        float xg[NF];
        #pragma unroll
        for (int f = 0; f < NF; ++f) xg[f] = xrow[s_idx[f]];

        float h0[NH];
        #pragma unroll
        for (int h = 0; h < NH; ++h) h0[h] = s_be0[h];
        #pragma unroll
        for (int f = 0; f < NF; ++f) {
            #pragma unroll
            for (int h = 0; h < NH; ++h)
                h0[h] = fmaf(xg[f], s_We0[f * NH + h], h0[h]);
        }
        // no ReLU on h0

        float h1[NL];
        #pragma unroll
        for (int l = 0; l < NL; ++l) h1[l] = s_be1[l];
        #pragma unroll
        for (int h = 0; h < NH; ++h) {
            #pragma unroll
            for (int l = 0; l < NL; ++l)
                h1[l] = fmaf(h0[h], s_We1[h * NL + l], h1[l]);
        }
        #pragma unroll
        for (int l = 0; l < NL; ++l) h1[l] = fmaxf(h1[l], 0.0f);

        float zz[NL];
        #pragma unroll
        for (int m = 0; m < NL; ++m) zz[m] = s_bl[m];
        #pragma unroll
        for (int l = 0; l < NL; ++l) {
            #pragma unroll
            for (int m = 0; m < NL; ++m)
                zz[m] = fmaf(h1[l], s_Wl[l * NL + m], zz[m]);
        }
        #pragma unroll
        for (int m = 0; m < NL; ++m) zz[m] = fmaxf(zz[m], 0.0f);

        float d0[NH];
        #pragma unroll
        for (int h = 0; h < NH; ++h) d0[h] = s_bd0[h];
        #pragma unroll
        for (int l = 0; l < NL; ++l) {
            #pragma unroll
            for (int h = 0; h < NH; ++h)
                d0[h] = fmaf(zz[l], s_Wd0[l * NH + h], d0[h]);
        }
        // no ReLU on d0

        float d1[NF];
        #pragma unroll
        for (int f = 0; f < NF; ++f) d1[f] = s_bd1[f];
        #pragma unroll
        for (int h = 0; h < NH; ++h) {
            #pragma unroll
            for (int f = 0; f < NF; ++f)
                d1[f] = fmaf(d0[h], s_Wd1[h * NF + f], d1[f]);
        }

        const int t = tid >> 4, r16 = tid & 15;
        #pragma unroll
        for (int kc = 0; kc < 4; ++kc) {
            short8 hi, lo;
            #pragma unroll
            for (int j = 0; j < 8; ++j) {
                float v = fmaxf(d1[kc * 8 + j], 0.0f);   // relu on d1
                unsigned short h = f2bf_rne(v);
                hi[j] = (short)h;
                lo[j] = (short)f2bf_rne(v - bf2f(h));
            }
            const int u = (t * 4 + kc) * 16 + r16;
            *reinterpret_cast<short8*>(&sAhi[u * 8]) = hi;
            *reinterpret_cast<short8*>(&sAlo[u * 8]) = lo;
        }
    }
    __syncthreads();

    // ---- phase 2: swapped-operand MFMA GEMM + sigmoid + dwordx4 stores ----
    {
        const int w   = tid >> 6;     // wave id: row-tiles [4w, 4w+4)
        const int l   = tid & 63;
        const int r16 = l & 15;       // output row within tile
        const int cq  = (l >> 4) * 4; // output col quad base within col-tile

        // A-side fragments for this wave's 4 row-tiles (d1), loaded once.
        short8 ahi[4], alo[4];
        #pragma unroll
        for (int i = 0; i < 4; ++i) {
            const int rt = w * 4 + i;
            ahi[i] = *reinterpret_cast<const short8*>(&sAhi[(rt * 64 + l) * 8]);
            alo[i] = *reinterpret_cast<const short8*>(&sAlo[(rt * 64 + l) * 8]);
        }

        #pragma unroll
        for (int ct = 0; ct < 16; ++ct) {
            const short8 bhi = *reinterpret_cast<const short8*>(&sBhi[(ct * 64 + l) * 8]);
            const short8 blo = *reinterpret_cast<const short8*>(&sBlo[(ct * 64 + l) * 8]);
            const floatx4 binit = *reinterpret_cast<const floatx4*>(bo + e * ND + ct * 16 + cq);

            #pragma unroll
            for (int i = 0; i < 4; ++i) {
                const int rt = w * 4 + i;
                floatx4 acc = binit;
                // swapped: Wo-frag in A slot, d1-frag in B slot -> transposed D
                acc = __builtin_amdgcn_mfma_f32_16x16x32_bf16(bhi, ahi[i], acc, 0, 0, 0);
                acc = __builtin_amdgcn_mfma_f32_16x16x32_bf16(blo, ahi[i], acc, 0, 0, 0);
                acc = __builtin_amdgcn_mfma_f32_16x16x32_bf16(bhi, alo[i], acc, 0, 0, 0);

                floatx4 o;
                o.x = sigf(acc[0]);
                o.y = sigf(acc[1]);
                o.z = sigf(acc[2]);
                o.w = sigf(acc[3]);
                float* po = out + ((long)e * NB + b0 + rt * 16 + r16) * ND + ct * 16 + cq;
                *reinterpret_cast<floatx4*>(po) = o;   // plain dwordx4 (L2 merges)
            }
        }
    }
}

extern "C" void kernel_launch(void* const* d_in, const int* in_sizes, int n_in,
                              void* d_out, int out_size, void* d_ws, size_t ws_size,
                              hipStream_t stream) {
    const float* x   = (const float*)d_in[0];
    const int*   idx = (const int*)  d_in[1];
    const float* We0 = (const float*)d_in[2];
    const float* be0 = (const float*)d_in[3];
    const float* We1 = (const float*)d_in[4];
    const float* be1 = (const float*)d_in[5];
    const float* Wl  = (const float*)d_in[6];
    const float* bl  = (const float*)d_in[7];
    const float* Wd0 = (const float*)d_in[8];
    const float* bd0 = (const float*)d_in[9];
    const float* Wd1 = (const float*)d_in[10];
    const float* bd1 = (const float*)d_in[11];
    const float* Wo  = (const float*)d_in[12];
    const float* bo  = (const float*)d_in[13];
    float* out = (float*)d_out;

    dim3 grid(NB / BT, NE);
    dim3 block(256);
    hipLaunchKernelGGL(bagae_mfma, grid, block, 0, stream,
                       x, idx, We0, be0, We1, be1, Wl, bl,
                       Wd0, bd0, Wd1, bd1, Wo, bo, out);
}

// Round 10
// 168.700 us; speedup vs baseline: 1.0839x; 1.0839x over previous
//
#include <hip/hip_runtime.h>
#include <hip/hip_bf16.h>

#define NE 100
#define NB 4096
#define ND 256
#define NF 32
#define NH 16
#define NL 8
#define BT 256   // batch rows per block

typedef float    floatx4 __attribute__((ext_vector_type(4)));
typedef _Float16 half8   __attribute__((ext_vector_type(8)));

__device__ __forceinline__ float sigf(float a) {
    return __builtin_amdgcn_rcpf(1.0f + __expf(-a));
}

// Fused: phase1 per-row MLP (fp32 VALU) -> fp16 fragments in LDS ->
// phase2 [256x32]@[32x256] via ONE mfma_f32_16x16x32_f16 per tile,
// swapped operands (Wo-frag in A slot, d1-frag in B slot) -> lane holds
// 4 consecutive OUTPUT columns of one row -> NT dwordx4 stores.
// Identical fragment construction on both operands cancels the HW k-map
// (hardware-verified by R8/R9 passing). fp16 single-term error ~1e-4,
// far under the 3.9e-3 absmax floor that pure-fp32 R5 already shows.
__global__ __launch_bounds__(256, 3)
void bagae_mfma(const float* __restrict__ x,
                const int* __restrict__ idx,
                const float* __restrict__ We0, const float* __restrict__ be0,
                const float* __restrict__ We1, const float* __restrict__ be1,
                const float* __restrict__ Wl,  const float* __restrict__ bl,
                const float* __restrict__ Wd0, const float* __restrict__ bd0,
                const float* __restrict__ Wd1, const float* __restrict__ bd1,
                const float* __restrict__ Wo,  const float* __restrict__ bo,
                float* __restrict__ out)
{
    __shared__ _Float16 sA[BT * NF];   // 16 KB, fragment-ordered d1 (fp16)
    __shared__ _Float16 sB[ND * NF];   // 16 KB, fragment-ordered Wo (fp16)
    __shared__ float s_We0[NF * NH];
    __shared__ float s_We1[NH * NL];
    __shared__ float s_Wl [NL * NL];
    __shared__ float s_Wd0[NL * NH];
    __shared__ float s_Wd1[NH * NF];
    __shared__ float s_be0[NH], s_be1[NL], s_bl[NL], s_bd0[NH], s_bd1[NF];
    __shared__ int   s_idx[NF];

    const int tid = threadIdx.x;
    const int e   = blockIdx.y;
    const int b0  = blockIdx.x * BT;

    // ---- stage small per-estimator weights ----
    {
        const float* We0e = We0 + e * (NF * NH);
        const float* Wd1e = Wd1 + e * (NH * NF);
        for (int i = tid; i < NF * NH; i += 256) { s_We0[i] = We0e[i]; s_Wd1[i] = Wd1e[i]; }
        if (tid < NH * NL) { s_We1[tid] = We1[e * NH * NL + tid];
                             s_Wd0[tid] = Wd0[e * NL * NH + tid]; }
        if (tid < NL * NL) { s_Wl[tid]  = Wl [e * NL * NL + tid]; }
        if (tid < NF)      { s_idx[tid] = idx[e * NF + tid];
                             s_bd1[tid] = bd1[e * NF + tid]; }
        if (tid < NH)      { s_be0[tid] = be0[e * NH + tid];
                             s_bd0[tid] = bd0[e * NH + tid]; }
        if (tid < NL)      { s_be1[tid] = be1[e * NL + tid];
                             s_bl [tid] = bl [e * NL + tid]; }
    }

    // ---- stage B = Wo_e column tid as fp16 fragments ----
    // unit u(tile,kc,i16) = tile*64 + kc*16 + i16 (16B units); lane l of
    // tile t reads unit t*64+l -> linear, conflict-free.
    {
        const float* Woe = Wo + (long)e * NF * ND;
        float wcol[NF];
        #pragma unroll
        for (int k = 0; k < NF; ++k) wcol[k] = Woe[k * ND + tid];   // coalesced
        const int ct = tid >> 4, c16 = tid & 15;
        #pragma unroll
        for (int kc = 0; kc < 4; ++kc) {
            half8 v;
            #pragma unroll
            for (int j = 0; j < 8; ++j) v[j] = (_Float16)wcol[kc * 8 + j];
            const int u = (ct * 4 + kc) * 16 + c16;
            *reinterpret_cast<half8*>(&sB[u * 8]) = v;
        }
    }
    __syncthreads();

    // ---- phase 1: per-row MLP chain -> d1[32] (relu) -> A fragments ----
    {
        const float* xrow = x + (long)(b0 + tid) * ND;

        float xg[NF];
        #pragma unroll
        for (int f = 0; f < NF; ++f) xg[f] = xrow[s_idx[f]];

        float h0[NH];
        #pragma unroll
        for (int h = 0; h < NH; ++h) h0[h] = s_be0[h];
        #pragma unroll
        for (int f = 0; f < NF; ++f) {
            #pragma unroll
            for (int h = 0; h < NH; ++h)
                h0[h] = fmaf(xg[f], s_We0[f * NH + h], h0[h]);
        }
        // no ReLU on h0

        float h1[NL];
        #pragma unroll
        for (int l = 0; l < NL; ++l) h1[l] = s_be1[l];
        #pragma unroll
        for (int h = 0; h < NH; ++h) {
            #pragma unroll
            for (int l = 0; l < NL; ++l)
                h1[l] = fmaf(h0[h], s_We1[h * NL + l], h1[l]);
        }
        #pragma unroll
        for (int l = 0; l < NL; ++l) h1[l] = fmaxf(h1[l], 0.0f);

        float zz[NL];
        #pragma unroll
        for (int m = 0; m < NL; ++m) zz[m] = s_bl[m];
        #pragma unroll
        for (int l = 0; l < NL; ++l) {
            #pragma unroll
            for (int m = 0; m < NL; ++m)
                zz[m] = fmaf(h1[l], s_Wl[l * NL + m], zz[m]);
        }
        #pragma unroll
        for (int m = 0; m < NL; ++m) zz[m] = fmaxf(zz[m], 0.0f);

        float d0[NH];
        #pragma unroll
        for (int h = 0; h < NH; ++h) d0[h] = s_bd0[h];
        #pragma unroll
        for (int l = 0; l < NL; ++l) {
            #pragma unroll
            for (int h = 0; h < NH; ++h)
                d0[h] = fmaf(zz[l], s_Wd0[l * NH + h], d0[h]);
        }
        // no ReLU on d0

        float d1[NF];
        #pragma unroll
        for (int f = 0; f < NF; ++f) d1[f] = s_bd1[f];
        #pragma unroll
        for (int h = 0; h < NH; ++h) {
            #pragma unroll
            for (int f = 0; f < NF; ++f)
                d1[f] = fmaf(d0[h], s_Wd1[h * NF + f], d1[f]);
        }

        const int t = tid >> 4, r16 = tid & 15;
        #pragma unroll
        for (int kc = 0; kc < 4; ++kc) {
            half8 v;
            #pragma unroll
            for (int j = 0; j < 8; ++j)
                v[j] = (_Float16)fmaxf(d1[kc * 8 + j], 0.0f);   // relu on d1
            const int u = (t * 4 + kc) * 16 + r16;
            *reinterpret_cast<half8*>(&sA[u * 8]) = v;
        }
    }
    __syncthreads();

    // ---- phase 2: swapped-operand fp16 MFMA + sigmoid + NT dwordx4 ----
    {
        const int w   = tid >> 6;     // wave id: row-tiles [4w, 4w+4)
        const int l   = tid & 63;
        const int r16 = l & 15;       // output row within tile
        const int cq  = (l >> 4) * 4; // output col quad base within col-tile

        // all B-frags (Wo) and this wave's A-frags (d1) in registers upfront
        half8 bfr[16];
        #pragma unroll
        for (int ct = 0; ct < 16; ++ct)
            bfr[ct] = *reinterpret_cast<const half8*>(&sB[(ct * 64 + l) * 8]);
        half8 afr[4];
        #pragma unroll
        for (int i = 0; i < 4; ++i)
            afr[i] = *reinterpret_cast<const half8*>(&sA[((w * 4 + i) * 64 + l) * 8]);

        #pragma unroll
        for (int i = 0; i < 4; ++i) {
            const int rt = w * 4 + i;
            float* prow = out + ((long)e * NB + b0 + rt * 16 + r16) * ND + cq;
            #pragma unroll
            for (int ct = 0; ct < 16; ++ct) {
                floatx4 acc = *reinterpret_cast<const floatx4*>(bo + e * ND + ct * 16 + cq);
                // swapped: Wo-frag in A slot, d1-frag in B slot -> transposed D
                acc = __builtin_amdgcn_mfma_f32_16x16x32_f16(bfr[ct], afr[i], acc, 0, 0, 0);
                floatx4 o;
                o.x = sigf(acc[0]);
                o.y = sigf(acc[1]);
                o.z = sigf(acc[2]);
                o.w = sigf(acc[3]);
                __builtin_nontemporal_store(o, reinterpret_cast<floatx4*>(prow + ct * 16));
            }
        }
    }
}

extern "C" void kernel_launch(void* const* d_in, const int* in_sizes, int n_in,
                              void* d_out, int out_size, void* d_ws, size_t ws_size,
                              hipStream_t stream) {
    const float* x   = (const float*)d_in[0];
    const int*   idx = (const int*)  d_in[1];
    const float* We0 = (const float*)d_in[2];
    const float* be0 = (const float*)d_in[3];
    const float* We1 = (const float*)d_in[4];
    const float* be1 = (const float*)d_in[5];
    const float* Wl  = (const float*)d_in[6];
    const float* bl  = (const float*)d_in[7];
    const float* Wd0 = (const float*)d_in[8];
    const float* bd0 = (const float*)d_in[9];
    const float* Wd1 = (const float*)d_in[10];
    const float* bd1 = (const float*)d_in[11];
    const float* Wo  = (const float*)d_in[12];
    const float* bo  = (const float*)d_in[13];
    float* out = (float*)d_out;

    dim3 grid(NB / BT, NE);
    dim3 block(256);
    hipLaunchKernelGGL(bagae_mfma, grid, block, 0, stream,
                       x, idx, We0, be0, We1, be1, Wl, bl,
                       Wd0, bd0, Wd1, bd1, Wo, bo, out);
}

// Round 11
// 118.968 us; speedup vs baseline: 1.5370x; 1.4180x over previous
//
#include <hip/hip_runtime.h>
#include <hip/hip_bf16.h>

#define NE 100
#define NB 4096
#define ND 256
#define NF 32
#define NH 16
#define NL 8
#define BT 256        // batch rows per block
#define S_REP 264     // repack row stride in floats (264 mod 32 = 8 -> bank stagger)

typedef float    floatx4 __attribute__((ext_vector_type(4)));
typedef _Float16 half8   __attribute__((ext_vector_type(8)));

__device__ __forceinline__ float sigf(float a) {
    return __builtin_amdgcn_rcpf(1.0f + __expf(-a));
}

// phase1 per-row MLP (fp32 VALU) -> fp16 fragments in LDS ->
// phase2 swapped-operand mfma_f32_16x16x32_f16 (verified R9/R10) ->
// sigmoid -> per-wave LDS repack (16x256 tile) -> FULL-ROW NT dwordx4
// stores (64 lanes x 16B = one 1KB row per instruction = R5's proven
// store pattern). Repack pool aliases the dead fragment buffers.
__global__ __launch_bounds__(256, 2)
void bagae_mfma(const float* __restrict__ x,
                const int* __restrict__ idx,
                const float* __restrict__ We0, const float* __restrict__ be0,
                const float* __restrict__ We1, const float* __restrict__ be1,
                const float* __restrict__ Wl,  const float* __restrict__ bl,
                const float* __restrict__ Wd0, const float* __restrict__ bd0,
                const float* __restrict__ Wd1, const float* __restrict__ bd1,
                const float* __restrict__ Wo,  const float* __restrict__ bo,
                float* __restrict__ out)
{
    // 4 waves x 16 rows x S_REP floats = 67.6 KB; fragment arrays alias the
    // front 32 KB (dead once frags are loaded to registers; barrier-separated).
    __shared__ float sPool[4 * 16 * S_REP];
    __shared__ float s_We0[NF * NH];
    __shared__ float s_We1[NH * NL];
    __shared__ float s_Wl [NL * NL];
    __shared__ float s_Wd0[NL * NH];
    __shared__ float s_Wd1[NH * NF];
    __shared__ float s_be0[NH], s_be1[NL], s_bl[NL], s_bd0[NH], s_bd1[NF];
    __shared__ int   s_idx[NF];

    _Float16* sA = reinterpret_cast<_Float16*>(sPool);            // BT*NF fp16 = 16 KB
    _Float16* sB = reinterpret_cast<_Float16*>(sPool) + BT * NF;  // ND*NF fp16 = 16 KB

    const int tid = threadIdx.x;
    const int e   = blockIdx.y;
    const int b0  = blockIdx.x * BT;

    // ---- stage small per-estimator weights ----
    {
        const float* We0e = We0 + e * (NF * NH);
        const float* Wd1e = Wd1 + e * (NH * NF);
        for (int i = tid; i < NF * NH; i += 256) { s_We0[i] = We0e[i]; s_Wd1[i] = Wd1e[i]; }
        if (tid < NH * NL) { s_We1[tid] = We1[e * NH * NL + tid];
                             s_Wd0[tid] = Wd0[e * NL * NH + tid]; }
        if (tid < NL * NL) { s_Wl[tid]  = Wl [e * NL * NL + tid]; }
        if (tid < NF)      { s_idx[tid] = idx[e * NF + tid];
                             s_bd1[tid] = bd1[e * NF + tid]; }
        if (tid < NH)      { s_be0[tid] = be0[e * NH + tid];
                             s_bd0[tid] = bd0[e * NH + tid]; }
        if (tid < NL)      { s_be1[tid] = be1[e * NL + tid];
                             s_bl [tid] = bl [e * NL + tid]; }
    }

    // ---- stage B = Wo_e column tid as fp16 fragments ----
    // unit u(tile,kc,i16) = tile*64 + kc*16 + i16 (16B units); lane l of
    // tile t reads unit t*64+l -> linear, conflict-free.
    {
        const float* Woe = Wo + (long)e * NF * ND;
        float wcol[NF];
        #pragma unroll
        for (int k = 0; k < NF; ++k) wcol[k] = Woe[k * ND + tid];   // coalesced
        const int ct = tid >> 4, c16 = tid & 15;
        #pragma unroll
        for (int kc = 0; kc < 4; ++kc) {
            half8 v;
            #pragma unroll
            for (int j = 0; j < 8; ++j) v[j] = (_Float16)wcol[kc * 8 + j];
            const int u = (ct * 4 + kc) * 16 + c16;
            *reinterpret_cast<half8*>(&sB[u * 8]) = v;
        }
    }
    __syncthreads();

    // ---- phase 1: per-row MLP chain -> d1[32] (relu) -> A fragments ----
    {
        const float* xrow = x + (long)(b0 + tid) * ND;

        float xg[NF];
        #pragma unroll
        for (int f = 0; f < NF; ++f) xg[f] = xrow[s_idx[f]];

        float h0[NH];
        #pragma unroll
        for (int h = 0; h < NH; ++h) h0[h] = s_be0[h];
        #pragma unroll
        for (int f = 0; f < NF; ++f) {
            #pragma unroll
            for (int h = 0; h < NH; ++h)
                h0[h] = fmaf(xg[f], s_We0[f * NH + h], h0[h]);
        }
        // no ReLU on h0

        float h1[NL];
        #pragma unroll
        for (int l = 0; l < NL; ++l) h1[l] = s_be1[l];
        #pragma unroll
        for (int h = 0; h < NH; ++h) {
            #pragma unroll
            for (int l = 0; l < NL; ++l)
                h1[l] = fmaf(h0[h], s_We1[h * NL + l], h1[l]);
        }
        #pragma unroll
        for (int l = 0; l < NL; ++l) h1[l] = fmaxf(h1[l], 0.0f);

        float zz[NL];
        #pragma unroll
        for (int m = 0; m < NL; ++m) zz[m] = s_bl[m];
        #pragma unroll
        for (int l = 0; l < NL; ++l) {
            #pragma unroll
            for (int m = 0; m < NL; ++m)
                zz[m] = fmaf(h1[l], s_Wl[l * NL + m], zz[m]);
        }
        #pragma unroll
        for (int m = 0; m < NL; ++m) zz[m] = fmaxf(zz[m], 0.0f);

        float d0[NH];
        #pragma unroll
        for (int h = 0; h < NH; ++h) d0[h] = s_bd0[h];
        #pragma unroll
        for (int l = 0; l < NL; ++l) {
            #pragma unroll
            for (int h = 0; h < NH; ++h)
                d0[h] = fmaf(zz[l], s_Wd0[l * NH + h], d0[h]);
        }
        // no ReLU on d0

        float d1[NF];
        #pragma unroll
        for (int f = 0; f < NF; ++f) d1[f] = s_bd1[f];
        #pragma unroll
        for (int h = 0; h < NH; ++h) {
            #pragma unroll
            for (int f = 0; f < NF; ++f)
                d1[f] = fmaf(d0[h], s_Wd1[h * NF + f], d1[f]);
        }

        const int t = tid >> 4, r16 = tid & 15;
        #pragma unroll
        for (int kc = 0; kc < 4; ++kc) {
            half8 v;
            #pragma unroll
            for (int j = 0; j < 8; ++j)
                v[j] = (_Float16)fmaxf(d1[kc * 8 + j], 0.0f);   // relu on d1
            const int u = (t * 4 + kc) * 16 + r16;
            *reinterpret_cast<half8*>(&sA[u * 8]) = v;
        }
    }
    __syncthreads();

    // ---- phase 2: load fragments to registers, then free the pool ----
    const int w   = tid >> 6;     // wave id: row-tiles [4w, 4w+4)
    const int l   = tid & 63;
    const int r16 = l & 15;       // output row within tile
    const int cq  = (l >> 4) * 4; // output col quad base within col-tile

    half8 bfr[16];
    #pragma unroll
    for (int ct = 0; ct < 16; ++ct)
        bfr[ct] = *reinterpret_cast<const half8*>(&sB[(ct * 64 + l) * 8]);
    half8 afr[4];
    #pragma unroll
    for (int i = 0; i < 4; ++i)
        afr[i] = *reinterpret_cast<const half8*>(&sA[((w * 4 + i) * 64 + l) * 8]);

    __syncthreads();   // all frags in registers; sPool now owned as repack space

    // ---- MFMA + sigmoid -> per-wave repack -> full-row NT stores ----
    {
        float* rep = &sPool[w * 16 * S_REP];   // this wave's 16x256 tile (padded)

        #pragma unroll
        for (int i = 0; i < 4; ++i) {
            const int rt = w * 4 + i;

            // compute & scatter one 16x256 row-tile into LDS
            #pragma unroll
            for (int ct = 0; ct < 16; ++ct) {
                floatx4 acc = *reinterpret_cast<const floatx4*>(bo + e * ND + ct * 16 + cq);
                // swapped: Wo-frag in A slot, d1-frag in B slot -> transposed D
                acc = __builtin_amdgcn_mfma_f32_16x16x32_f16(bfr[ct], afr[i], acc, 0, 0, 0);
                floatx4 o;
                o.x = sigf(acc[0]);
                o.y = sigf(acc[1]);
                o.z = sigf(acc[2]);
                o.w = sigf(acc[3]);
                *reinterpret_cast<floatx4*>(&rep[r16 * S_REP + ct * 16 + cq]) = o;
            }
            // in-wave LDS ordering: DS pipe is in-order per wave; same-array
            // accesses keep the compiler from reordering across this point.

            // read back rows and stream out: one full 1KB row per instruction
            float* obase = out + ((long)e * NB + b0 + rt * 16) * ND + 4 * l;
            #pragma unroll
            for (int r = 0; r < 16; ++r) {
                floatx4 v = *reinterpret_cast<const floatx4*>(&rep[r * S_REP + 4 * l]);
                __builtin_nontemporal_store(v, reinterpret_cast<floatx4*>(obase + (long)r * ND));
            }
        }
    }
}

extern "C" void kernel_launch(void* const* d_in, const int* in_sizes, int n_in,
                              void* d_out, int out_size, void* d_ws, size_t ws_size,
                              hipStream_t stream) {
    const float* x   = (const float*)d_in[0];
    const int*   idx = (const int*)  d_in[1];
    const float* We0 = (const float*)d_in[2];
    const float* be0 = (const float*)d_in[3];
    const float* We1 = (const float*)d_in[4];
    const float* be1 = (const float*)d_in[5];
    const float* Wl  = (const float*)d_in[6];
    const float* bl  = (const float*)d_in[7];
    const float* Wd0 = (const float*)d_in[8];
    const float* bd0 = (const float*)d_in[9];
    const float* Wd1 = (const float*)d_in[10];
    const float* bd1 = (const float*)d_in[11];
    const float* Wo  = (const float*)d_in[12];
    const float* bo  = (const float*)d_in[13];
    float* out = (float*)d_out;

    dim3 grid(NB / BT, NE);
    dim3 block(256);
    hipLaunchKernelGGL(bagae_mfma, grid, block, 0, stream,
                       x, idx, We0, be0, We1, be1, Wl, bl,
                       Wd0, bd0, Wd1, bd1, Wo, bo, out);
}